// Round 2
// baseline (5953.073 us; speedup 1.0000x reference)
//
#include <hip/hip_runtime.h>

#define N_PATHS   300000
#define REALBZ    1024
#define D         32
#define GT_FLOATS (2 * 96 * 64)   /* 12288 floats = 48 KiB: Gt[par][j][v] */
#define H2_FLOATS (4096 * 32)     /* 131072 floats = 512 KiB: h2[v0*64+v1][k] */

__device__ __forceinline__ float fsig(float x) {
    return __builtin_amdgcn_rcpf(1.f + __expf(-x));
}
__device__ __forceinline__ float ftanh(float x) {
    float e = __expf(-2.f * x);
    return fmaf(2.f, __builtin_amdgcn_rcpf(1.f + e), -1.f);   // (1-e)/(1+e)
}

// Gt[par][j][v] = b_ih[j] + (j<64 ? b_hh[j] : 0) + sum_k w_ih[j,k]*emb_par[v,k]
// Transposed (v innermost) so the per-j gather in the GRU spans 256B, not 24KB.
// b_hh r/z parts folded here (they sit outside the r* multiply); b_hh_n cannot be.
__global__ void build_g_kernel(const float* __restrict__ all_emb,
                               const float* __restrict__ edge_emb,
                               const float* __restrict__ w_ih,
                               const float* __restrict__ b_ih,
                               const float* __restrict__ b_hh,
                               float* __restrict__ Gt)
{
    int t = blockIdx.x * blockDim.x + threadIdx.x;
    if (t >= GT_FLOATS) return;
    int par = t / 6144;
    int rem = t % 6144;
    int j   = rem >> 6;
    int v   = rem & 63;
    const float* emb = (par ? edge_emb : all_emb) + v * D;
    float s = b_ih[j] + (j < 64 ? b_hh[j] : 0.f);
#pragma unroll
    for (int k = 0; k < D; ++k)
        s = fmaf(w_ih[j * D + k], emb[k], s);
    Gt[t] = s;
}

// One GRU step. h in VGPRs; weights from LDS float4 (uniform addr -> broadcast);
// input gates gathered from transposed Gt (gt already offset by parity).
__device__ __forceinline__ void gru_step(float (&h)[D],
                                         const float4* __restrict__ sw4,
                                         const float* __restrict__ gt, int v,
                                         const float* __restrict__ b_hh)
{
    float hn[D];
#pragma unroll
    for (int j = 0; j < D; ++j) {
        float dr = 0.f, dz = 0.f, dn = b_hh[64 + j];
#pragma unroll
        for (int m = 0; m < 8; ++m) {
            float4 wr = sw4[       j * 8 + m];
            float4 wz = sw4[256 +  j * 8 + m];
            float4 wn = sw4[512 +  j * 8 + m];
            float h0 = h[4*m], h1 = h[4*m+1], h2v = h[4*m+2], h3 = h[4*m+3];
            dr = fmaf(wr.x, h0, dr); dr = fmaf(wr.y, h1, dr);
            dr = fmaf(wr.z, h2v, dr); dr = fmaf(wr.w, h3, dr);
            dz = fmaf(wz.x, h0, dz); dz = fmaf(wz.y, h1, dz);
            dz = fmaf(wz.z, h2v, dz); dz = fmaf(wz.w, h3, dz);
            dn = fmaf(wn.x, h0, dn); dn = fmaf(wn.y, h1, dn);
            dn = fmaf(wn.z, h2v, dn); dn = fmaf(wn.w, h3, dn);
        }
        float r = fsig(gt[j * 64 + v] + dr);           // b_ih+b_hh folded in Gt
        float z = fsig(gt[(32 + j) * 64 + v] + dz);
        float n = ftanh(fmaf(r, dn, gt[(64 + j) * 64 + v]));
        hn[j] = fmaf(z, h[j] - n, n);                  // (1-z)*n + z*h
    }
#pragma unroll
    for (int j = 0; j < D; ++j) h[j] = hn[j];
}

// h2[v0*64+v1][0:32] = hidden state after steps l=0 (entity v0), l=1 (relation v1)
__global__ __launch_bounds__(256, 1) void build_h2_kernel(
    const float* __restrict__ w_hh, const float* __restrict__ b_hh,
    const float* __restrict__ Gt, float* __restrict__ h2)
{
    __shared__ float4 sw4[768];
    const float4* w4 = (const float4*)w_hh;
    for (int i = threadIdx.x; i < 768; i += 256) sw4[i] = w4[i];
    __syncthreads();

    int t = blockIdx.x * blockDim.x + threadIdx.x;   // 0..4095
    int v0 = t >> 6, v1 = t & 63;
    float h[D];
#pragma unroll
    for (int k = 0; k < D; ++k) h[k] = 0.f;
    gru_step(h, sw4, Gt,        v0, b_hh);   // l=0, entity parity
    gru_step(h, sw4, Gt + 6144, v1, b_hh);   // l=1, relation parity

    float4* out = (float4*)(h2 + (size_t)t * D);
#pragma unroll
    for (int m = 0; m < 8; ++m)
        out[m] = make_float4(h[4*m], h[4*m+1], h[4*m+2], h[4*m+3]);
}

template <int L_START>
__global__ __launch_bounds__(256, 1) void gru_path_kernel(
    const int*   __restrict__ path,
    const int*   __restrict__ path_idx,
    const float* __restrict__ Gt,
    const float* __restrict__ h2,
    const float* __restrict__ w_hh,
    const float* __restrict__ b_hh,
    const float* __restrict__ w_lin,
    const float* __restrict__ b_lin,
    float*       __restrict__ score)
{
    __shared__ float4 sw4[768];
    const float4* w4 = (const float4*)w_hh;
    for (int i = threadIdx.x; i < 768; i += 256) sw4[i] = w4[i];
    __syncthreads();

    int p = blockIdx.x * blockDim.x + threadIdx.x;
    if (p >= N_PATHS) return;

    float h[D];
    if (L_START == 2) {
        int v0 = path[p * 5 + 0];
        int v1 = path[p * 5 + 1];
        const float4* hp = (const float4*)(h2 + (size_t)(v0 * 64 + v1) * D);
#pragma unroll
        for (int m = 0; m < 8; ++m) {
            float4 x = hp[m];
            h[4*m] = x.x; h[4*m+1] = x.y; h[4*m+2] = x.z; h[4*m+3] = x.w;
        }
    } else {
#pragma unroll
        for (int k = 0; k < D; ++k) h[k] = 0.f;
    }

    // l rolled: one ~step-sized body (~30KB) fits I$; 3 (or 5) iterations
#pragma unroll 1
    for (int l = L_START; l < 5; ++l) {
        int vv = path[p * 5 + l];
        gru_step(h, sw4, Gt + (l & 1) * 6144, vv, b_hh);
    }

    float s = b_lin[0];
#pragma unroll
    for (int k = 0; k < D; ++k) s = fmaf(w_lin[k], h[k], s);

    atomicAdd(&score[path_idx[p]], s);
}

extern "C" void kernel_launch(void* const* d_in, const int* in_sizes, int n_in,
                              void* d_out, int out_size, void* d_ws, size_t ws_size,
                              hipStream_t stream)
{
    // 0 users 1 path 2 path_idx 3 all_emb 4 edge_emb 5 virtual_emb(unused)
    // 6 w_ih 7 w_hh 8 b_ih 9 b_hh 10 w_lin 11 b_lin
    const int*   path     = (const int*)  d_in[1];
    const int*   path_idx = (const int*)  d_in[2];
    const float* all_emb  = (const float*)d_in[3];
    const float* edge_emb = (const float*)d_in[4];
    const float* w_ih     = (const float*)d_in[6];
    const float* w_hh     = (const float*)d_in[7];
    const float* b_ih     = (const float*)d_in[8];
    const float* b_hh     = (const float*)d_in[9];
    const float* w_lin    = (const float*)d_in[10];
    const float* b_lin    = (const float*)d_in[11];

    float* Gt = (float*)d_ws;
    float* h2 = (float*)d_ws + GT_FLOATS;
    bool use_h2 = ws_size >= (size_t)(GT_FLOATS + H2_FLOATS) * sizeof(float);

    float* score = (float*)d_out;
    hipMemsetAsync(d_out, 0, (size_t)out_size * sizeof(float), stream);

    build_g_kernel<<<(GT_FLOATS + 255) / 256, 256, 0, stream>>>(
        all_emb, edge_emb, w_ih, b_ih, b_hh, Gt);

    int grid = (N_PATHS + 255) / 256;
    if (use_h2) {
        build_h2_kernel<<<16, 256, 0, stream>>>(w_hh, b_hh, Gt, h2);
        gru_path_kernel<2><<<grid, 256, 0, stream>>>(
            path, path_idx, Gt, h2, w_hh, b_hh, w_lin, b_lin, score);
    } else {
        gru_path_kernel<0><<<grid, 256, 0, stream>>>(
            path, path_idx, Gt, h2, w_hh, b_hh, w_lin, b_lin, score);
    }
}

// Round 3
// 538.285 us; speedup vs baseline: 11.0593x; 11.0593x over previous
//
#include <hip/hip_runtime.h>

#define N_PATHS   300000
#define REALBZ    1024
#define D         32
#define GT_FLOATS (2 * 96 * 64)   /* 12288 floats = 48 KiB: Gt[par][j][v] */
#define H2_FLOATS (4096 * 32)     /* 131072 floats = 512 KiB: h2[v0*64+v1][k] */

#define LOG2E  1.44269504088896340736f

__device__ __forceinline__ float fsig(float x) {
    // 1/(1+exp(-x)) : v_mul + v_exp + v_add + v_rcp
    float e = __builtin_amdgcn_exp2f(-LOG2E * x);
    return __builtin_amdgcn_rcpf(1.f + e);
}
__device__ __forceinline__ float ftanh(float x) {
    // (1-e)/(1+e), e = exp(-2x) : v_mul + v_exp + v_add + v_rcp + v_fma
    float e = __builtin_amdgcn_exp2f(-2.f * LOG2E * x);
    return fmaf(2.f, __builtin_amdgcn_rcpf(1.f + e), -1.f);
}

// Gt[par][j][v] = b_ih[j] + (j<64 ? b_hh[j] : 0) + sum_k w_ih[j,k]*emb_par[v,k]
// v innermost: a wave's 64-lane gather of gt[j*64+v] touches 4 cache lines.
// b_hh r/z parts folded (they sit outside the r* multiply); b_hh_n cannot be.
__global__ void build_g_kernel(const float* __restrict__ all_emb,
                               const float* __restrict__ edge_emb,
                               const float* __restrict__ w_ih,
                               const float* __restrict__ b_ih,
                               const float* __restrict__ b_hh,
                               float* __restrict__ Gt)
{
    int t = blockIdx.x * blockDim.x + threadIdx.x;
    if (t >= GT_FLOATS) return;
    int par = t / 6144;
    int rem = t % 6144;
    int j   = rem >> 6;
    int v   = rem & 63;
    const float* emb = (par ? edge_emb : all_emb) + v * D;
    float s = b_ih[j] + (j < 64 ? b_hh[j] : 0.f);
#pragma unroll
    for (int k = 0; k < D; ++k)
        s = fmaf(w_ih[j * D + k], emb[k], s);
    Gt[t] = s;
}

// One GRU step. h in VGPRs. w_hh/b_hh are wave-uniform const __restrict__
// global reads -> backend emits s_load (SGPR operands, zero VGPR pressure).
// DO NOT stage weights in LDS: that moves them to VGPRs and spills (R2: 8GB
// scratch traffic, 11x regression).
__device__ __forceinline__ void gru_step(float (&h)[D],
                                         const float* __restrict__ w_hh,
                                         const float* __restrict__ b_hh,
                                         const float* __restrict__ gt, int v)
{
    float hn[D];
#pragma unroll
    for (int j = 0; j < D; ++j) {
        float dr = 0.f, dz = 0.f, dn = b_hh[64 + j];
#pragma unroll
        for (int k = 0; k < D; ++k) {
            float hk = h[k];
            dr = fmaf(w_hh[j * D + k],        hk, dr);
            dz = fmaf(w_hh[(32 + j) * D + k], hk, dz);
            dn = fmaf(w_hh[(64 + j) * D + k], hk, dn);
        }
        float r = fsig(gt[j * 64 + v] + dr);            // b_ih+b_hh folded in Gt
        float z = fsig(gt[(32 + j) * 64 + v] + dz);
        float n = ftanh(fmaf(r, dn, gt[(64 + j) * 64 + v]));
        hn[j] = fmaf(z, h[j] - n, n);                   // (1-z)*n + z*h
    }
#pragma unroll
    for (int j = 0; j < D; ++j) h[j] = hn[j];
}

// h2[v0*64+v1][0:32] = hidden state after steps l=0 (entity v0), l=1 (rel v1)
__global__ void build_h2_kernel(const float* __restrict__ w_hh,
                                const float* __restrict__ b_hh,
                                const float* __restrict__ Gt,
                                float* __restrict__ h2)
{
    int t = blockIdx.x * blockDim.x + threadIdx.x;   // 0..4095
    if (t >= 4096) return;
    int v0 = t >> 6, v1 = t & 63;
    float h[D];
#pragma unroll
    for (int k = 0; k < D; ++k) h[k] = 0.f;
    gru_step(h, w_hh, b_hh, Gt,        v0);   // l=0, entity parity
    gru_step(h, w_hh, b_hh, Gt + 6144, v1);   // l=1, relation parity

    float4* out = (float4*)(h2 + (size_t)t * D);
#pragma unroll
    for (int m = 0; m < 8; ++m)
        out[m] = make_float4(h[4*m], h[4*m+1], h[4*m+2], h[4*m+3]);
}

template <int L_START>
__global__ void gru_path_kernel(
    const int*   __restrict__ path,
    const int*   __restrict__ path_idx,
    const float* __restrict__ Gt,
    const float* __restrict__ h2,
    const float* __restrict__ w_hh,
    const float* __restrict__ b_hh,
    const float* __restrict__ w_lin,
    const float* __restrict__ b_lin,
    float*       __restrict__ score)
{
    int p = blockIdx.x * blockDim.x + threadIdx.x;
    if (p >= N_PATHS) return;

    float h[D];
    if (L_START == 2) {
        int v0 = path[p * 5 + 0];
        int v1 = path[p * 5 + 1];
        const float4* hp = (const float4*)(h2 + (size_t)(v0 * 64 + v1) * D);
#pragma unroll
        for (int m = 0; m < 8; ++m) {
            float4 x = hp[m];
            h[4*m] = x.x; h[4*m+1] = x.y; h[4*m+2] = x.z; h[4*m+3] = x.w;
        }
    } else {
#pragma unroll
        for (int k = 0; k < D; ++k) h[k] = 0.f;
    }

    // l rolled: one step-sized body fits I$; 3 (or 5) iterations
#pragma unroll 1
    for (int l = L_START; l < 5; ++l) {
        int vv = path[p * 5 + l];
        gru_step(h, w_hh, b_hh, Gt + (l & 1) * 6144, vv);
    }

    float s = b_lin[0];
#pragma unroll
    for (int k = 0; k < D; ++k) s = fmaf(w_lin[k], h[k], s);

    atomicAdd(&score[path_idx[p]], s);
}

extern "C" void kernel_launch(void* const* d_in, const int* in_sizes, int n_in,
                              void* d_out, int out_size, void* d_ws, size_t ws_size,
                              hipStream_t stream)
{
    // 0 users 1 path 2 path_idx 3 all_emb 4 edge_emb 5 virtual_emb(unused)
    // 6 w_ih 7 w_hh 8 b_ih 9 b_hh 10 w_lin 11 b_lin
    const int*   path     = (const int*)  d_in[1];
    const int*   path_idx = (const int*)  d_in[2];
    const float* all_emb  = (const float*)d_in[3];
    const float* edge_emb = (const float*)d_in[4];
    const float* w_ih     = (const float*)d_in[6];
    const float* w_hh     = (const float*)d_in[7];
    const float* b_ih     = (const float*)d_in[8];
    const float* b_hh     = (const float*)d_in[9];
    const float* w_lin    = (const float*)d_in[10];
    const float* b_lin    = (const float*)d_in[11];

    float* Gt = (float*)d_ws;
    float* h2 = (float*)d_ws + GT_FLOATS;
    bool use_h2 = ws_size >= (size_t)(GT_FLOATS + H2_FLOATS) * sizeof(float);

    float* score = (float*)d_out;
    hipMemsetAsync(d_out, 0, (size_t)out_size * sizeof(float), stream);

    build_g_kernel<<<(GT_FLOATS + 255) / 256, 256, 0, stream>>>(
        all_emb, edge_emb, w_ih, b_ih, b_hh, Gt);

    int grid = (N_PATHS + 255) / 256;
    if (use_h2) {
        build_h2_kernel<<<16, 256, 0, stream>>>(w_hh, b_hh, Gt, h2);
        gru_path_kernel<2><<<grid, 256, 0, stream>>>(
            path, path_idx, Gt, h2, w_hh, b_hh, w_lin, b_lin, score);
    } else {
        gru_path_kernel<0><<<grid, 256, 0, stream>>>(
            path, path_idx, Gt, h2, w_hh, b_hh, w_lin, b_lin, score);
    }
}

// Round 4
// 289.222 us; speedup vs baseline: 20.5831x; 1.8612x over previous
//
#include <hip/hip_runtime.h>

#define N_PATHS   300000
#define REALBZ    1024
#define D         32
#define GT_FLOATS (2 * 96 * 64)   /* 12288 floats = 48 KiB: Gt[par][j][v] */

typedef __attribute__((ext_vector_type(8))) short short8;   // 8 bf16 = 4 VGPR
typedef __attribute__((ext_vector_type(4))) float f32x4;    // MFMA C/D

#define LOG2E 1.44269504088896340736f

__device__ __forceinline__ float fsig(float x) {
    float e = __builtin_amdgcn_exp2f(-LOG2E * x);
    return __builtin_amdgcn_rcpf(1.f + e);
}
__device__ __forceinline__ float ftanh(float x) {
    float e = __builtin_amdgcn_exp2f(-2.f * LOG2E * x);
    return fmaf(2.f, __builtin_amdgcn_rcpf(1.f + e), -1.f);
}
__device__ __forceinline__ unsigned short bf16_rne(float f) {
    unsigned u = __float_as_uint(f);
    u += 0x7FFF + ((u >> 16) & 1);
    return (unsigned short)(u >> 16);
}
__device__ __forceinline__ float bf16_to_f(unsigned short s) {
    return __uint_as_float(((unsigned)s) << 16);
}

// ---------- prep: Gt[par][j][v] fp32 (for exact h2 build) ----------
__global__ void build_g_kernel(const float* __restrict__ all_emb,
                               const float* __restrict__ edge_emb,
                               const float* __restrict__ w_ih,
                               const float* __restrict__ b_ih,
                               const float* __restrict__ b_hh,
                               float* __restrict__ Gt)
{
    int t = blockIdx.x * blockDim.x + threadIdx.x;
    if (t >= GT_FLOATS) return;
    int par = t / 6144;
    int rem = t % 6144;
    int j   = rem >> 6;
    int v   = rem & 63;
    const float* emb = (par ? edge_emb : all_emb) + v * D;
    float s = b_ih[j] + (j < 64 ? b_hh[j] : 0.f);
#pragma unroll
    for (int k = 0; k < D; ++k)
        s = fmaf(w_ih[j * D + k], emb[k], s);
    Gt[t] = s;
}

// scalar GRU step (weights via wave-uniform s_load; used only for h2 build)
__device__ __forceinline__ void gru_step(float (&h)[D],
                                         const float* __restrict__ w_hh,
                                         const float* __restrict__ b_hh,
                                         const float* __restrict__ gt, int v)
{
    float hn[D];
#pragma unroll
    for (int j = 0; j < D; ++j) {
        float dr = 0.f, dz = 0.f, dn = b_hh[64 + j];
#pragma unroll
        for (int k = 0; k < D; ++k) {
            float hk = h[k];
            dr = fmaf(w_hh[j * D + k],        hk, dr);
            dz = fmaf(w_hh[(32 + j) * D + k], hk, dz);
            dn = fmaf(w_hh[(64 + j) * D + k], hk, dn);
        }
        float r = fsig(gt[j * 64 + v] + dr);
        float z = fsig(gt[(32 + j) * 64 + v] + dz);
        float n = ftanh(fmaf(r, dn, gt[(64 + j) * 64 + v]));
        hn[j] = fmaf(z, h[j] - n, n);
    }
#pragma unroll
    for (int j = 0; j < D; ++j) h[j] = hn[j];
}

// h2b[v0*64+v1][0:32] (bf16) = hidden after l=0 (entity v0), l=1 (relation v1)
__global__ void build_h2_kernel(const float* __restrict__ w_hh,
                                const float* __restrict__ b_hh,
                                const float* __restrict__ Gt,
                                unsigned short* __restrict__ h2b)
{
    int t = blockIdx.x * blockDim.x + threadIdx.x;
    if (t >= 4096) return;
    int v0 = t >> 6, v1 = t & 63;
    float h[D];
#pragma unroll
    for (int k = 0; k < D; ++k) h[k] = 0.f;
    gru_step(h, w_hh, b_hh, Gt,        v0);
    gru_step(h, w_hh, b_hh, Gt + 6144, v1);
#pragma unroll
    for (int k = 0; k < D; ++k) h2b[t * D + k] = bf16_rne(h[k]);
}

// bf16 images: embt[2][64][32] (par0=all_emb rows 0..63, par1=edge_emb), W row-major
__global__ void cvt_kernel(const float* __restrict__ all_emb,
                           const float* __restrict__ edge_emb,
                           const float* __restrict__ w_ih,
                           const float* __restrict__ w_hh,
                           unsigned short* __restrict__ embt,
                           unsigned short* __restrict__ Wihb,
                           unsigned short* __restrict__ Whhb)
{
    int t = blockIdx.x * blockDim.x + threadIdx.x;
    const int E = 64 * 32;
    if (t < E)              embt[t]        = bf16_rne(all_emb[t]);
    else if (t < 2 * E)     embt[t]        = bf16_rne(edge_emb[t - E]);
    else if (t < 2*E + 3072)      Wihb[t - 2*E]        = bf16_rne(w_ih[t - 2*E]);
    else if (t < 2*E + 6144)      Whhb[t - 2*E - 3072] = bf16_rne(w_hh[t - 2*E - 3072]);
}

// ---------- main: 32 paths/wave, MFMA gates, LDS h round-trip ----------
// MFMA facts (m89-verified): C/D col=lane&15 row=quad*4+reg; A[m=lane&15][k=quad*8+i].
// B-frag: lane element i <-> B[k=quad*8+i][n=lane&15], i.e. load W[n][k] row-contig.
// r/z/n for one (path,j) share lane&reg across N-tiles -> no cross-lane elementwise.
__global__ __launch_bounds__(256, 2) void gru_mfma_kernel(
    const int*   __restrict__ path,
    const int*   __restrict__ path_idx,
    const unsigned short* __restrict__ embt,
    const unsigned short* __restrict__ Wihb,
    const unsigned short* __restrict__ Whhb,
    const unsigned short* __restrict__ h2b,
    const float* __restrict__ b_ih,
    const float* __restrict__ b_hh,
    const float* __restrict__ w_lin,
    const float* __restrict__ b_lin,
    float*       __restrict__ score)
{
    // per-wave h buffer: 32 rows x 40 shorts (80B rows: conflict-min b128 reads)
    __shared__ short hbuf[4][32 * 40];
    const int tid  = threadIdx.x;
    const int wv   = tid >> 6;
    const int lane = tid & 63;
    const int lc   = lane & 15;
    const int quad = lane >> 4;
    const int pbase = (blockIdx.x * 4 + wv) * 32;

    // weights as B-frags, held in VGPRs for the whole kernel (48 VGPRs)
    short8 Bih[6], Bhh[6];
#pragma unroll
    for (int nt = 0; nt < 6; ++nt) {
        Bih[nt] = *(const short8*)(Wihb + (nt * 16 + lc) * 32 + quad * 8);
        Bhh[nt] = *(const short8*)(Whhb + (nt * 16 + lc) * 32 + quad * 8);
    }
    // biases: fold b_ih+b_hh into r/z init; keep b_ih_n (x-acc) / b_hh_n (h-acc) split
    float brz[4], bxn[2], bhn[2];
#pragma unroll
    for (int nt = 0; nt < 4; ++nt) brz[nt] = b_ih[nt * 16 + lc] + b_hh[nt * 16 + lc];
#pragma unroll
    for (int jh = 0; jh < 2; ++jh) {
        bxn[jh] = b_ih[64 + jh * 16 + lc];
        bhn[jh] = b_hh[64 + jh * 16 + lc];
    }

    // init LDS h rows from h2 memo (bf16)
#pragma unroll
    for (int it = 0; it < 2; ++it) {
        int ploc = it * 16 + (lane >> 2);
        int qtr  = lane & 3;
        int pid  = min(pbase + ploc, N_PATHS - 1);
        int v0 = path[pid * 5 + 0], v1 = path[pid * 5 + 1];
        short8 src = *(const short8*)((const short*)h2b + (v0 * 64 + v1) * 32 + qtr * 8);
        *(short8*)(&hbuf[wv][ploc * 40 + qtr * 8]) = src;
    }
    __syncthreads();

    // fp32 state in C-layout registers (carries full precision across steps)
    float hold[2][2][4];
#pragma unroll
    for (int mt = 0; mt < 2; ++mt)
#pragma unroll
        for (int jh = 0; jh < 2; ++jh)
#pragma unroll
            for (int q = 0; q < 4; ++q) {
                int p = mt * 16 + quad * 4 + q, j = jh * 16 + lc;
                hold[mt][jh][q] = bf16_to_f((unsigned short)hbuf[wv][p * 40 + j]);
            }

    int vrow[2];
#pragma unroll
    for (int mt = 0; mt < 2; ++mt)
        vrow[mt] = min(pbase + mt * 16 + lc, N_PATHS - 1) * 5;

#pragma unroll 1
    for (int l = 2; l < 5; ++l) {
        int par = l & 1;   // even l = entity, odd = relation
        short8 xa[2], ha[2];
#pragma unroll
        for (int mt = 0; mt < 2; ++mt) {
            int v = path[vrow[mt] + l];
            xa[mt] = *(const short8*)((const short*)embt + (par * 64 + v) * 32 + quad * 8);
            ha[mt] = *(const short8*)(&hbuf[wv][(mt * 16 + lc) * 40 + quad * 8]);
        }

        f32x4 rz[2][4], xn[2][2], hn[2][2];
#pragma unroll
        for (int mt = 0; mt < 2; ++mt) {
#pragma unroll
            for (int nt = 0; nt < 4; ++nt) {
                f32x4 acc = {brz[nt], brz[nt], brz[nt], brz[nt]};
                acc = __builtin_amdgcn_mfma_f32_16x16x32_bf16(xa[mt], Bih[nt], acc, 0, 0, 0);
                acc = __builtin_amdgcn_mfma_f32_16x16x32_bf16(ha[mt], Bhh[nt], acc, 0, 0, 0);
                rz[mt][nt] = acc;
            }
#pragma unroll
            for (int jh = 0; jh < 2; ++jh) {
                f32x4 ax = {bxn[jh], bxn[jh], bxn[jh], bxn[jh]};
                xn[mt][jh] = __builtin_amdgcn_mfma_f32_16x16x32_bf16(xa[mt], Bih[4 + jh], ax, 0, 0, 0);
                f32x4 ah = {bhn[jh], bhn[jh], bhn[jh], bhn[jh]};
                hn[mt][jh] = __builtin_amdgcn_mfma_f32_16x16x32_bf16(ha[mt], Bhh[4 + jh], ah, 0, 0, 0);
            }
        }

        // elementwise (same lane/reg across tiles), then pack pairs -> LDS
#pragma unroll
        for (int mt = 0; mt < 2; ++mt)
#pragma unroll
            for (int jh = 0; jh < 2; ++jh)
#pragma unroll
                for (int q = 0; q < 4; ++q) {
                    float r = fsig(rz[mt][jh][q]);
                    float z = fsig(rz[mt][2 + jh][q]);
                    float n = ftanh(fmaf(r, hn[mt][jh][q], xn[mt][jh][q]));
                    float hv = fmaf(z, hold[mt][jh][q] - n, n);
                    hold[mt][jh][q] = hv;
                    unsigned my = bf16_rne(hv);
                    unsigned other = ((unsigned)__shfl_xor((int)my, 1, 64)) & 0xFFFFu;
                    unsigned packed = (lane & 1) ? ((my << 16) | other)
                                                 : ((other << 16) | my);
                    int p  = mt * 16 + quad * 4 + q;
                    int jb = jh * 16 + (lc & ~1);
                    *(unsigned*)(&hbuf[wv][p * 40 + jb]) = packed;  // pair writes same data
                }
        __syncthreads();
    }

    // epilogue: per-path dot(w_lin, h) + b_lin, 4 lanes/path, shfl-reduce, atomic
#pragma unroll
    for (int it = 0; it < 2; ++it) {
        int ploc = it * 16 + (lane >> 2);
        int qtr  = lane & 3;
        short8 hvv = *(const short8*)(&hbuf[wv][ploc * 40 + qtr * 8]);
        float s = 0.f;
#pragma unroll
        for (int i = 0; i < 8; ++i)
            s = fmaf(bf16_to_f((unsigned short)hvv[i]), w_lin[qtr * 8 + i], s);
        s += __shfl_xor(s, 1, 64);
        s += __shfl_xor(s, 2, 64);
        int pid = pbase + ploc;
        if (qtr == 0 && pid < N_PATHS)
            atomicAdd(&score[path_idx[pid]], s + b_lin[0]);
    }
}

extern "C" void kernel_launch(void* const* d_in, const int* in_sizes, int n_in,
                              void* d_out, int out_size, void* d_ws, size_t ws_size,
                              hipStream_t stream)
{
    // 0 users 1 path 2 path_idx 3 all_emb 4 edge_emb 5 virtual_emb(unused)
    // 6 w_ih 7 w_hh 8 b_ih 9 b_hh 10 w_lin 11 b_lin
    const int*   path     = (const int*)  d_in[1];
    const int*   path_idx = (const int*)  d_in[2];
    const float* all_emb  = (const float*)d_in[3];
    const float* edge_emb = (const float*)d_in[4];
    const float* w_ih     = (const float*)d_in[6];
    const float* w_hh     = (const float*)d_in[7];
    const float* b_ih     = (const float*)d_in[8];
    const float* b_hh     = (const float*)d_in[9];
    const float* w_lin    = (const float*)d_in[10];
    const float* b_lin    = (const float*)d_in[11];

    // ws layout (bytes): Gt fp32 @0 (48K) | h2b @49152 (256K) | embt @311296 (8K)
    //                    | Wihb @319488 (6K) | Whhb @325632 (6K)  -- total 324K
    char* ws = (char*)d_ws;
    float*          Gt   = (float*)ws;
    unsigned short* h2b  = (unsigned short*)(ws + 49152);
    unsigned short* embt = (unsigned short*)(ws + 311296);
    unsigned short* Wihb = (unsigned short*)(ws + 319488);
    unsigned short* Whhb = (unsigned short*)(ws + 325632);

    float* score = (float*)d_out;
    hipMemsetAsync(d_out, 0, (size_t)out_size * sizeof(float), stream);

    build_g_kernel<<<(GT_FLOATS + 255) / 256, 256, 0, stream>>>(
        all_emb, edge_emb, w_ih, b_ih, b_hh, Gt);
    cvt_kernel<<<(2 * 64 * 32 + 6144 + 255) / 256, 256, 0, stream>>>(
        all_emb, edge_emb, w_ih, w_hh, embt, Wihb, Whhb);
    build_h2_kernel<<<16, 256, 0, stream>>>(w_hh, b_hh, Gt, h2b);

    int grid = (N_PATHS + 127) / 128;   // 128 paths/block (4 waves x 32)
    gru_mfma_kernel<<<grid, 256, 0, stream>>>(
        path, path_idx, embt, Wihb, Whhb, h2b,
        b_ih, b_hh, w_lin, b_lin, score);
}

// Round 5
// 200.399 us; speedup vs baseline: 29.7060x; 1.4432x over previous
//
#include <hip/hip_runtime.h>

#define N_PATHS 300000
#define REALBZ  1024
#define D       32

typedef __attribute__((ext_vector_type(8))) short  short8;   // 8 bf16 = 4 VGPR (MFMA A/B)
typedef __attribute__((ext_vector_type(4))) short  short4v;
typedef __attribute__((ext_vector_type(4))) float  f32x4;    // MFMA C/D

#define LOG2E 1.44269504088896340736f

__device__ __forceinline__ float fsig(float x) {
    float e = __builtin_amdgcn_exp2f(-LOG2E * x);
    return __builtin_amdgcn_rcpf(1.f + e);
}
__device__ __forceinline__ float ftanh(float x) {
    float e = __builtin_amdgcn_exp2f(-2.f * LOG2E * x);
    return fmaf(2.f, __builtin_amdgcn_rcpf(1.f + e), -1.f);
}
__device__ __forceinline__ unsigned short bf16_rne(float f) {
    unsigned u = __float_as_uint(f);
    u += 0x7FFF + ((u >> 16) & 1);
    return (unsigned short)(u >> 16);
}
__device__ __forceinline__ float bf16_to_f(unsigned short s) {
    return __uint_as_float(((unsigned)s) << 16);
}
__device__ __forceinline__ unsigned pack2(float a, float b) {
    return (unsigned)bf16_rne(a) | ((unsigned)bf16_rne(b) << 16);
}

// ---------------- single prep dispatch ----------------
// blocks 0..511: h2b[v0*64+v1][j] (bf16) = GRU steps l=0 (all_emb[v0]), l=1 (edge_emb[v1]).
//   Stage 1 (32 thr): h1[v0][j] with h=0 (gh = b_hh). Stage 2 (256 thr): 8 v1 x 32 j.
//   Fully j-parallel -> wide, unlike R3/R4's 16-block serial build (~the hidden 170us).
// blocks 512..555: bf16 conversions (embt/Wihb/Whhb) + zero d_out.
__global__ void prep_kernel(const int* __restrict__ path,
                            const float* __restrict__ all_emb,
                            const float* __restrict__ edge_emb,
                            const float* __restrict__ w_ih,
                            const float* __restrict__ w_hh,
                            const float* __restrict__ b_ih,
                            const float* __restrict__ b_hh,
                            unsigned short* __restrict__ embt,
                            unsigned short* __restrict__ Wihb,
                            unsigned short* __restrict__ Whhb,
                            unsigned short* __restrict__ h2b,
                            float* __restrict__ score)
{
    const int b = blockIdx.x, tid = threadIdx.x;
    if (b < 512) {
        __shared__ float h1[32];
        const int v0 = b >> 3;
        if (tid < 32) {
            int j = tid;
            const float* x = all_emb + v0 * D;
            float gr = b_ih[j], gz = b_ih[32 + j], gn = b_ih[64 + j];
#pragma unroll
            for (int k = 0; k < D; ++k) {
                float xk = x[k];
                gr = fmaf(w_ih[j * D + k],        xk, gr);
                gz = fmaf(w_ih[(32 + j) * D + k], xk, gz);
                gn = fmaf(w_ih[(64 + j) * D + k], xk, gn);
            }
            float r = fsig(gr + b_hh[j]);
            float z = fsig(gz + b_hh[32 + j]);
            float n = ftanh(fmaf(r, b_hh[64 + j], gn));
            h1[j] = (1.f - z) * n;                       // h=0
        }
        __syncthreads();
        const int v1 = (b & 7) * 8 + (tid >> 5);
        const int j  = tid & 31;
        const float* x = edge_emb + v1 * D;
        float gr = b_ih[j], gz = b_ih[32 + j], gn = b_ih[64 + j];
        float dr = b_hh[j], dz = b_hh[32 + j], dn = b_hh[64 + j];
#pragma unroll
        for (int k = 0; k < D; ++k) {
            float xk = x[k], hk = h1[k];
            gr = fmaf(w_ih[j * D + k],        xk, gr);
            gz = fmaf(w_ih[(32 + j) * D + k], xk, gz);
            gn = fmaf(w_ih[(64 + j) * D + k], xk, gn);
            dr = fmaf(w_hh[j * D + k],        hk, dr);
            dz = fmaf(w_hh[(32 + j) * D + k], hk, dz);
            dn = fmaf(w_hh[(64 + j) * D + k], hk, dn);
        }
        float r = fsig(gr + dr);
        float z = fsig(gz + dz);
        float n = ftanh(fmaf(r, dn, gn));
        float h2v = fmaf(z, h1[j] - n, n);
        h2b[(v0 * 64 + v1) * D + j] = bf16_rne(h2v);
    } else {
        int t = (b - 512) * 256 + tid;
        if (t < 2048)        embt[t] = bf16_rne(all_emb[t]);        // entity rows 0..63
        else if (t < 4096)   embt[t] = bf16_rne(edge_emb[t - 2048]);
        else if (t < 7168)   Wihb[t - 4096] = bf16_rne(w_ih[t - 4096]);
        else if (t < 10240)  Whhb[t - 7168] = bf16_rne(w_hh[t - 7168]);
        else if (t < 10240 + REALBZ) score[t - 10240] = 0.f;
    }
}

// ---------------- main: 32 paths/wave, gates^T MFMA, block = 1 wave ----------------
// Orientation: D[m=j][n=path]: A = W (lane m=j_local holds W[j][k=quad*8+i]),
// B = x^T / h^T (lane n=path holds x[path][k=quad*8+i]).  C/D: col=lane&15=path,
// row=quad*4+reg=j_local.  So h_new sits path-per-lane: LDS writeback is
// 2x ds_write_b64, next-step B-frag is 1x ds_read_b128 (was 16 shfl+16 writes in R4).
__global__ __launch_bounds__(64) void gru_mfma_kernel(
    const int* __restrict__ path,
    const int* __restrict__ path_idx,
    const unsigned short* __restrict__ embt,
    const unsigned short* __restrict__ Wihb,
    const unsigned short* __restrict__ Whhb,
    const unsigned short* __restrict__ h2b,
    const float* __restrict__ b_ih,
    const float* __restrict__ b_hh,
    const float* __restrict__ w_lin,
    const float* __restrict__ b_lin,
    float* __restrict__ score)
{
    __shared__ short hbuf[32 * 40];            // 32 paths x 32 feat, pad to 40 (80B rows)
    const int lane = threadIdx.x;              // block = 1 wave: barrier couples nothing
    const int lc   = lane & 15;
    const int quad = lane >> 4;
    const int pbase = blockIdx.x * 32;         // 300000/32 = 9375 blocks exactly

    // W as A-frags, resident (48 VGPR). jt 0..3 = r,z rows 0..63; 4..5 = n rows 64..95.
    short8 Aih[6], Ahh[6];
#pragma unroll
    for (int jt = 0; jt < 6; ++jt) {
        Aih[jt] = *(const short8*)(Wihb + (jt * 16 + lc) * D + quad * 8);
        Ahh[jt] = *(const short8*)(Whhb + (jt * 16 + lc) * D + quad * 8);
    }
    // biases per (jt, reg): j = jt*16 + quad*4 + q  (r,z: b_ih+b_hh folded; n split)
    f32x4 brz[4], bxn[2], bhn[2];
#pragma unroll
    for (int jt = 0; jt < 4; ++jt)
#pragma unroll
        for (int q = 0; q < 4; ++q)
            brz[jt][q] = b_ih[jt * 16 + quad * 4 + q] + b_hh[jt * 16 + quad * 4 + q];
#pragma unroll
    for (int jh = 0; jh < 2; ++jh)
#pragma unroll
        for (int q = 0; q < 4; ++q) {
            bxn[jh][q] = b_ih[64 + jh * 16 + quad * 4 + q];
            bhn[jh][q] = b_hh[64 + jh * 16 + quad * 4 + q];
        }

    // init hbuf rows from h2 memo: lane -> (path p = lane&31, half hf = lane>>5)
    {
        int p  = lane & 31, hf = lane >> 5;
        int rb = (pbase + p) * 5;
        int v0 = path[rb], v1 = path[rb + 1];
        const short* src = (const short*)h2b + (v0 * 64 + v1) * D + hf * 16;
        *(short8*)(&hbuf[p * 40 + hf * 16])     = *(const short8*)(src);
        *(short8*)(&hbuf[p * 40 + hf * 16 + 8]) = *(const short8*)(src + 8);
    }
    // prefetch step indices (static after full unroll)
    int vs[2][3];
#pragma unroll
    for (int nt = 0; nt < 2; ++nt) {
        int rb = (pbase + nt * 16 + lc) * 5;
        vs[nt][0] = path[rb + 2]; vs[nt][1] = path[rb + 3]; vs[nt][2] = path[rb + 4];
    }
    __syncthreads();

    // fp32 h state in C-layout: hold[nt][jh][q] = h[path nt*16+lc][jh*16+quad*4+q]
    float hold[2][2][4];
#pragma unroll
    for (int nt = 0; nt < 2; ++nt)
#pragma unroll
        for (int jh = 0; jh < 2; ++jh) {
            short4v ld = *(const short4v*)(&hbuf[(nt * 16 + lc) * 40 + jh * 16 + quad * 4]);
#pragma unroll
            for (int q = 0; q < 4; ++q) hold[nt][jh][q] = bf16_to_f((unsigned short)ld[q]);
        }

#pragma unroll
    for (int l = 2; l < 5; ++l) {
        const int par = l & 1;
        short8 Bx[2], Bh[2];
#pragma unroll
        for (int nt = 0; nt < 2; ++nt) {
            Bx[nt] = *(const short8*)(embt + (par * 64 + vs[nt][l - 2]) * D + quad * 8);
            Bh[nt] = *(const short8*)(&hbuf[(nt * 16 + lc) * 40 + quad * 8]);
        }
#pragma unroll
        for (int nt = 0; nt < 2; ++nt) {
            f32x4 rz[4], xn[2], hn[2];
#pragma unroll
            for (int jt = 0; jt < 4; ++jt) {
                f32x4 acc = brz[jt];
                acc = __builtin_amdgcn_mfma_f32_16x16x32_bf16(Aih[jt], Bx[nt], acc, 0, 0, 0);
                acc = __builtin_amdgcn_mfma_f32_16x16x32_bf16(Ahh[jt], Bh[nt], acc, 0, 0, 0);
                rz[jt] = acc;
            }
#pragma unroll
            for (int jh = 0; jh < 2; ++jh) {
                xn[jh] = __builtin_amdgcn_mfma_f32_16x16x32_bf16(Aih[4 + jh], Bx[nt], bxn[jh], 0, 0, 0);
                hn[jh] = __builtin_amdgcn_mfma_f32_16x16x32_bf16(Ahh[4 + jh], Bh[nt], bhn[jh], 0, 0, 0);
            }
#pragma unroll
            for (int jh = 0; jh < 2; ++jh) {
                float hv[4];
#pragma unroll
                for (int q = 0; q < 4; ++q) {
                    float r = fsig(rz[jh][q]);
                    float z = fsig(rz[2 + jh][q]);
                    float n = ftanh(fmaf(r, hn[jh][q], xn[jh][q]));
                    hv[q] = fmaf(z, hold[nt][jh][q] - n, n);
                    hold[nt][jh][q] = hv[q];
                }
                uint2 d = make_uint2(pack2(hv[0], hv[1]), pack2(hv[2], hv[3]));
                *(uint2*)(&hbuf[(nt * 16 + lc) * 40 + jh * 16 + quad * 4]) = d;  // b64, 8B-aligned
            }
        }
        __syncthreads();   // 1-wave block: orders LDS write->read, couples no other wave
    }

    // epilogue in fp32 from hold: dot(w_lin, h) reduced across the 4 quads of each path
    float4 wl0 = *(const float4*)(w_lin + quad * 4);
    float4 wl1 = *(const float4*)(w_lin + 16 + quad * 4);
    float s[2];
#pragma unroll
    for (int nt = 0; nt < 2; ++nt) {
        float t = 0.f;
        t = fmaf(wl0.x, hold[nt][0][0], t); t = fmaf(wl0.y, hold[nt][0][1], t);
        t = fmaf(wl0.z, hold[nt][0][2], t); t = fmaf(wl0.w, hold[nt][0][3], t);
        t = fmaf(wl1.x, hold[nt][1][0], t); t = fmaf(wl1.y, hold[nt][1][1], t);
        t = fmaf(wl1.z, hold[nt][1][2], t); t = fmaf(wl1.w, hold[nt][1][3], t);
        t += __shfl_xor(t, 16, 64);
        t += __shfl_xor(t, 32, 64);
        s[nt] = t;
    }
    if (quad < 2) {
        int p = pbase + quad * 16 + lc;
        float val = (quad ? s[1] : s[0]) + b_lin[0];
        atomicAdd(&score[path_idx[p]], val);
    }
}

extern "C" void kernel_launch(void* const* d_in, const int* in_sizes, int n_in,
                              void* d_out, int out_size, void* d_ws, size_t ws_size,
                              hipStream_t stream)
{
    // 0 users 1 path 2 path_idx 3 all_emb 4 edge_emb 5 virtual_emb(unused)
    // 6 w_ih 7 w_hh 8 b_ih 9 b_hh 10 w_lin 11 b_lin
    const int*   path     = (const int*)  d_in[1];
    const int*   path_idx = (const int*)  d_in[2];
    const float* all_emb  = (const float*)d_in[3];
    const float* edge_emb = (const float*)d_in[4];
    const float* w_ih     = (const float*)d_in[6];
    const float* w_hh     = (const float*)d_in[7];
    const float* b_ih     = (const float*)d_in[8];
    const float* b_hh     = (const float*)d_in[9];
    const float* w_lin    = (const float*)d_in[10];
    const float* b_lin    = (const float*)d_in[11];

    // ws (bytes): embt @0 (8K) | Wihb @8192 (6K) | Whhb @14336 (6K) | h2b @20480 (256K)
    char* ws = (char*)d_ws;
    unsigned short* embt = (unsigned short*)ws;
    unsigned short* Wihb = (unsigned short*)(ws + 8192);
    unsigned short* Whhb = (unsigned short*)(ws + 14336);
    unsigned short* h2b  = (unsigned short*)(ws + 20480);

    float* score = (float*)d_out;

    prep_kernel<<<512 + 44, 256, 0, stream>>>(
        path, all_emb, edge_emb, w_ih, w_hh, b_ih, b_hh,
        embt, Wihb, Whhb, h2b, score);

    gru_mfma_kernel<<<N_PATHS / 32, 64, 0, stream>>>(
        path, path_idx, embt, Wihb, Whhb, h2b,
        b_ih, b_hh, w_lin, b_lin, score);
}

// Round 8
// 199.246 us; speedup vs baseline: 29.8780x; 1.0058x over previous
//
#include <hip/hip_runtime.h>

#define N_PATHS 300000
#define REALBZ  1024
#define D       32

typedef __attribute__((ext_vector_type(8))) short  short8;   // 8 bf16 = 4 VGPR (MFMA A/B)
typedef __attribute__((ext_vector_type(4))) float  f32x4;    // MFMA C/D
typedef __attribute__((ext_vector_type(4))) unsigned int uint4v;

#define LOG2E 1.44269504088896340736f

__device__ __forceinline__ float fsig(float x) {
    float e = __builtin_amdgcn_exp2f(-LOG2E * x);
    return __builtin_amdgcn_rcpf(1.f + e);
}
__device__ __forceinline__ float ftanh(float x) {
    float e = __builtin_amdgcn_exp2f(-2.f * LOG2E * x);
    return fmaf(2.f, __builtin_amdgcn_rcpf(1.f + e), -1.f);
}
__device__ __forceinline__ unsigned short bf16_rne(float f) {
    unsigned u = __float_as_uint(f);
    u += 0x7FFF + ((u >> 16) & 1);
    return (unsigned short)(u >> 16);
}
__device__ __forceinline__ float bf16_to_f(unsigned short s) {
    return __uint_as_float(((unsigned)s) << 16);
}
__device__ __forceinline__ unsigned pack2(float a, float b) {
    return (unsigned)bf16_rne(a) | ((unsigned)bf16_rne(b) << 16);
}

// ---------------- single prep dispatch ----------------
__global__ void prep_kernel(const int* __restrict__ path,
                            const float* __restrict__ all_emb,
                            const float* __restrict__ edge_emb,
                            const float* __restrict__ w_ih,
                            const float* __restrict__ w_hh,
                            const float* __restrict__ b_ih,
                            const float* __restrict__ b_hh,
                            unsigned short* __restrict__ embt,
                            unsigned short* __restrict__ Wihb,
                            unsigned short* __restrict__ Whhb,
                            unsigned short* __restrict__ h2b,
                            unsigned* __restrict__ pk,
                            float* __restrict__ score,
                            int do_pack)
{
    const int b = blockIdx.x, tid = threadIdx.x;
    if (b < 512) {
        __shared__ float gsh[96];
        __shared__ float h1[32];
        const int v0 = b >> 3;
        if (tid < 96) {                       // stage 1a: gate-parallel matvec
            const int j = tid & 31, g = tid >> 5;
            const float* x = all_emb + v0 * D;
            float acc = b_ih[g * 32 + j];
#pragma unroll
            for (int k = 0; k < D; ++k)
                acc = fmaf(w_ih[(g * 32 + j) * D + k], x[k], acc);
            gsh[tid] = acc;
        }
        __syncthreads();
        if (tid < 32) {                       // stage 1b: nonlinearity, h=0
            int j = tid;
            float r = fsig(gsh[j] + b_hh[j]);
            float z = fsig(gsh[32 + j] + b_hh[32 + j]);
            float n = ftanh(fmaf(r, b_hh[64 + j], gsh[64 + j]));
            h1[j] = (1.f - z) * n;
        }
        __syncthreads();
        const int v1 = (b & 7) * 8 + (tid >> 5);   // stage 2: 8 v1 x 32 j
        const int j  = tid & 31;
        const float* x = edge_emb + v1 * D;
        float gr = b_ih[j], gz = b_ih[32 + j], gn = b_ih[64 + j];
        float dr = b_hh[j], dz = b_hh[32 + j], dn = b_hh[64 + j];
#pragma unroll
        for (int k = 0; k < D; ++k) {
            float xk = x[k], hk = h1[k];
            gr = fmaf(w_ih[j * D + k],        xk, gr);
            gz = fmaf(w_ih[(32 + j) * D + k], xk, gz);
            gn = fmaf(w_ih[(64 + j) * D + k], xk, gn);
            dr = fmaf(w_hh[j * D + k],        hk, dr);
            dz = fmaf(w_hh[(32 + j) * D + k], hk, dz);
            dn = fmaf(w_hh[(64 + j) * D + k], hk, dn);
        }
        float r = fsig(gr + dr);
        float z = fsig(gz + dz);
        float n = ftanh(fmaf(r, dn, gn));
        h2b[(v0 * 64 + v1) * D + j] = bf16_rne(fmaf(z, h1[j] - n, n));
    } else if (b < 556) {
        int t = (b - 512) * 256 + tid;
        if (t < 2048)        embt[t] = bf16_rne(all_emb[t]);
        else if (t < 4096)   embt[t] = bf16_rne(edge_emb[t - 2048]);
        else if (t < 7168)   Wihb[t - 4096] = bf16_rne(w_ih[t - 4096]);
        else if (t < 10240)  Whhb[t - 7168] = bf16_rne(w_hh[t - 7168]);
        else if (t < 10240 + REALBZ) score[t - 10240] = 0.f;
    } else if (do_pack) {
        int t = (b - 556) * 256 + tid;
        if (t < N_PATHS) {
            const int* r = path + t * 5;
            pk[t] = (unsigned)r[0] | ((unsigned)r[1] << 6) | ((unsigned)r[2] << 12)
                  | ((unsigned)r[3] << 18) | ((unsigned)r[4] << 24);
        }
    }
}

// ---------------- main: gates^T MFMA, NO LDS storage, bpermute transpose ----------------
// D[m=j][n=path]. C/D: col=lane&15=path, row=quad*4+reg (m89). C->B transform:
// target (lc,qt) dword d needs source slot (jh=qt>>1, qs=2*(qt&1)+(d>>1), di=d&1).
// Bijective 4-call schedule: call c delivers dword d=2*((qt>>1)^(c>>1))+(c&1);
// source exposes R[(quad&1)^(c>>1)][c&1]; addr_lo(c=0,1)/addr_hi(c=2,3);
// target swaps halves when quad>=2.  (R6 bug: jh chosen by SOURCE quad — 2-to-1.)
template <int USE_PK>
__global__ __launch_bounds__(256) void gru_mfma_kernel(
    const int* __restrict__ path,
    const unsigned* __restrict__ pk,
    const int* __restrict__ path_idx,
    const unsigned short* __restrict__ embt,
    const unsigned short* __restrict__ Wihb,
    const unsigned short* __restrict__ Whhb,
    const unsigned short* __restrict__ h2b,
    const float* __restrict__ b_ih,
    const float* __restrict__ b_hh,
    const float* __restrict__ w_lin,
    const float* __restrict__ b_lin,
    float* __restrict__ score)
{
    const int lane = threadIdx.x & 63;
    const int lc   = lane & 15;
    const int quad = lane >> 4;
    const int wu   = blockIdx.x * 4 + (threadIdx.x >> 6);   // wave unit
    const int pbase = wu * 32;

    // W as A-frags, resident. jt 0..3 = r,z; 4..5 = n.
    short8 Aih[6], Ahh[6];
#pragma unroll
    for (int jt = 0; jt < 6; ++jt) {
        Aih[jt] = *(const short8*)(Wihb + (jt * 16 + lc) * D + quad * 8);
        Ahh[jt] = *(const short8*)(Whhb + (jt * 16 + lc) * D + quad * 8);
    }
    f32x4 brz[4], bxn[2], bhn[2];
#pragma unroll
    for (int jt = 0; jt < 4; ++jt)
#pragma unroll
        for (int q = 0; q < 4; ++q)
            brz[jt][q] = b_ih[jt * 16 + quad * 4 + q] + b_hh[jt * 16 + quad * 4 + q];
#pragma unroll
    for (int jh = 0; jh < 2; ++jh)
#pragma unroll
        for (int q = 0; q < 4; ++q) {
            bxn[jh][q] = b_ih[64 + jh * 16 + quad * 4 + q];
            bhn[jh][q] = b_hh[64 + jh * 16 + quad * 4 + q];
        }

    // per-nt path decode + init B-frag / hold directly from global h2b
    int vs[2][3];
    short8 Bh[2];
    float hold[2][2][4];
#pragma unroll
    for (int nt = 0; nt < 2; ++nt) {
        int p = min(pbase + nt * 16 + lc, N_PATHS - 1);
        int v0, v1;
        if (USE_PK) {
            unsigned w = pk[p];
            v0 = w & 63; v1 = (w >> 6) & 63;
            vs[nt][0] = (w >> 12) & 63; vs[nt][1] = (w >> 18) & 63; vs[nt][2] = (w >> 24) & 63;
        } else {
            const int* r = path + p * 5;
            v0 = r[0]; v1 = r[1];
            vs[nt][0] = r[2]; vs[nt][1] = r[3]; vs[nt][2] = r[4];
        }
        const unsigned short* hsrc = h2b + (v0 * 64 + v1) * D;
        Bh[nt] = *(const short8*)(hsrc + quad * 8);               // B-layout: 16B
#pragma unroll
        for (int jh = 0; jh < 2; ++jh) {                          // C-layout: 2x8B
            const unsigned short* c = hsrc + jh * 16 + quad * 4;
#pragma unroll
            for (int q = 0; q < 4; ++q) hold[nt][jh][q] = bf16_to_f(c[q]);
        }
    }

    // bpermute source-lane byte addresses (loop-invariant):
    // addr_lo: qs = 2*(quad&1) + (quad>>1); addr_hi: qs = 2*(quad&1) + ((quad>>1)^1)
    const int qlo = 2 * (quad & 1) + (quad >> 1);
    const int a_lo = 4 * (lc + 16 * qlo);
    const int a_hi = 4 * (lc + 16 * (qlo ^ 1));
    const bool hi = quad >= 2;
    const bool oddq = (quad & 1) != 0;

#pragma unroll
    for (int l = 2; l < 5; ++l) {
        const int par = l & 1;
        short8 Bx[2];
#pragma unroll
        for (int nt = 0; nt < 2; ++nt)
            Bx[nt] = *(const short8*)(embt + (par * 64 + vs[nt][l - 2]) * D + quad * 8);

#pragma unroll
        for (int nt = 0; nt < 2; ++nt) {
            f32x4 rz[4], xn[2], hn[2];
#pragma unroll
            for (int jt = 0; jt < 4; ++jt) {
                f32x4 acc = brz[jt];
                acc = __builtin_amdgcn_mfma_f32_16x16x32_bf16(Aih[jt], Bx[nt], acc, 0, 0, 0);
                acc = __builtin_amdgcn_mfma_f32_16x16x32_bf16(Ahh[jt], Bh[nt], acc, 0, 0, 0);
                rz[jt] = acc;
            }
#pragma unroll
            for (int jh = 0; jh < 2; ++jh) {
                xn[jh] = __builtin_amdgcn_mfma_f32_16x16x32_bf16(Aih[4 + jh], Bx[nt], bxn[jh], 0, 0, 0);
                hn[jh] = __builtin_amdgcn_mfma_f32_16x16x32_bf16(Ahh[4 + jh], Bh[nt], bhn[jh], 0, 0, 0);
            }
            unsigned R[2][2];
#pragma unroll
            for (int jh = 0; jh < 2; ++jh) {
                float hv[4];
#pragma unroll
                for (int q = 0; q < 4; ++q) {
                    float r = fsig(rz[jh][q]);
                    float z = fsig(rz[2 + jh][q]);
                    float n = ftanh(fmaf(r, hn[jh][q], xn[jh][q]));
                    hv[q] = fmaf(z, hold[nt][jh][q] - n, n);
                    hold[nt][jh][q] = hv[q];
                }
                R[jh][0] = pack2(hv[0], hv[1]);
                R[jh][1] = pack2(hv[2], hv[3]);
            }
            if (l < 4) {   // produce next-step B-frag; skip after last step
                // source-exposed values: call c -> R[(quad&1)^(c>>1)][c&1]
                unsigned v0c = oddq ? R[1][0] : R[0][0];   // c=0
                unsigned v1c = oddq ? R[1][1] : R[0][1];   // c=1
                unsigned v2c = oddq ? R[0][0] : R[1][0];   // c=2
                unsigned v3c = oddq ? R[0][1] : R[1][1];   // c=3
                unsigned r0 = (unsigned)__builtin_amdgcn_ds_bpermute(a_lo, (int)v0c);
                unsigned r1 = (unsigned)__builtin_amdgcn_ds_bpermute(a_lo, (int)v1c);
                unsigned r2 = (unsigned)__builtin_amdgcn_ds_bpermute(a_hi, (int)v2c);
                unsigned r3 = (unsigned)__builtin_amdgcn_ds_bpermute(a_hi, (int)v3c);
                uint4v t;
                t.x = hi ? r2 : r0;
                t.y = hi ? r3 : r1;
                t.z = hi ? r0 : r2;
                t.w = hi ? r1 : r3;
                Bh[nt] = __builtin_bit_cast(short8, t);
            }
        }
    }

    // epilogue: dot(w_lin, h) from fp32 hold, quad-reduce, one atomic per path
    float4 wl0 = *(const float4*)(w_lin + quad * 4);
    float4 wl1 = *(const float4*)(w_lin + 16 + quad * 4);
    float s[2];
#pragma unroll
    for (int nt = 0; nt < 2; ++nt) {
        float t = 0.f;
        t = fmaf(wl0.x, hold[nt][0][0], t); t = fmaf(wl0.y, hold[nt][0][1], t);
        t = fmaf(wl0.z, hold[nt][0][2], t); t = fmaf(wl0.w, hold[nt][0][3], t);
        t = fmaf(wl1.x, hold[nt][1][0], t); t = fmaf(wl1.y, hold[nt][1][1], t);
        t = fmaf(wl1.z, hold[nt][1][2], t); t = fmaf(wl1.w, hold[nt][1][3], t);
        t += __shfl_xor(t, 16, 64);
        t += __shfl_xor(t, 32, 64);
        s[nt] = t;
    }
    if (quad < 2) {
        int p = pbase + quad * 16 + lc;
        if (p < N_PATHS)
            atomicAdd(&score[path_idx[p]], (quad ? s[1] : s[0]) + b_lin[0]);
    }
}

extern "C" void kernel_launch(void* const* d_in, const int* in_sizes, int n_in,
                              void* d_out, int out_size, void* d_ws, size_t ws_size,
                              hipStream_t stream)
{
    // 0 users 1 path 2 path_idx 3 all_emb 4 edge_emb 5 virtual_emb(unused)
    // 6 w_ih 7 w_hh 8 b_ih 9 b_hh 10 w_lin 11 b_lin
    const int*   path     = (const int*)  d_in[1];
    const int*   path_idx = (const int*)  d_in[2];
    const float* all_emb  = (const float*)d_in[3];
    const float* edge_emb = (const float*)d_in[4];
    const float* w_ih     = (const float*)d_in[6];
    const float* w_hh     = (const float*)d_in[7];
    const float* b_ih     = (const float*)d_in[8];
    const float* b_hh     = (const float*)d_in[9];
    const float* w_lin    = (const float*)d_in[10];
    const float* b_lin    = (const float*)d_in[11];

    // ws (bytes): embt @0 (8K) | Wihb @8192 (6K) | Whhb @14336 (6K)
    //             | h2b @20480 (256K) | pk @282624 (1.2M)
    char* ws = (char*)d_ws;
    unsigned short* embt = (unsigned short*)ws;
    unsigned short* Wihb = (unsigned short*)(ws + 8192);
    unsigned short* Whhb = (unsigned short*)(ws + 14336);
    unsigned short* h2b  = (unsigned short*)(ws + 20480);
    unsigned*       pk   = (unsigned*)(ws + 282624);
    const int use_pk = (ws_size >= 282624 + (size_t)N_PATHS * 4) ? 1 : 0;

    float* score = (float*)d_out;

    const int pack_blocks = use_pk ? (N_PATHS + 255) / 256 : 0;
    prep_kernel<<<556 + pack_blocks, 256, 0, stream>>>(
        path, all_emb, edge_emb, w_ih, w_hh, b_ih, b_hh,
        embt, Wihb, Whhb, h2b, pk, score, use_pk);

    const int grid = (N_PATHS / 32 + 3) / 4;   // 9375 wave units, 4 waves/block
    if (use_pk)
        gru_mfma_kernel<1><<<grid, 256, 0, stream>>>(
            path, pk, path_idx, embt, Wihb, Whhb, h2b, b_ih, b_hh, w_lin, b_lin, score);
    else
        gru_mfma_kernel<0><<<grid, 256, 0, stream>>>(
            path, pk, path_idx, embt, Wihb, Whhb, h2b, b_ih, b_hh, w_lin, b_lin, score);
}